// Round 11
// baseline (1021.878 us; speedup 1.0000x reference)
//
#include <hip/hip_runtime.h>
#include <hip/hip_bf16.h>
#include <hip/hip_fp16.h>
#include <stdint.h>

#define H 4
#define HID 64
#define CDIM 256   /* = H*HID = IN = FC */
#define OUTC 4
#define ALPHA 0.2f
#define NW 16      /* number of float weight inputs (d_in[2..17]) */
#define MAXB 512   /* max buckets; NBUCK = ceil(Nn/256) <= 512 for Nn <= 131072 */
#define TILE1 4096 /* edges per pass1 tile (8 per thread x 512 threads) */

typedef __attribute__((ext_vector_type(8))) _Float16 f16x8;
typedef __attribute__((ext_vector_type(4))) float f32x4;

#define GLOBAL_AS(p) ((const __attribute__((address_space(1))) void*)(p))
#define LDS_AS(p)    ((__attribute__((address_space(3))) void*)(p))

// ---------------------------------------------------------------------------
// dtype detection (R2/R4/R5-proven; real answer on this harness: fp32, flag=0)
// ---------------------------------------------------------------------------
__global__ void detect_k(const uint32_t* __restrict__ xw, int* __restrict__ flag) {
    __shared__ int sd[256];
    int t = threadIdx.x;
    int hits = 0;
    for (int i = 0; i < 16; ++i) {
        uint32_t w = xw[t * 16 + i];
        uint32_t ex = (w >> 7) & 0xffu;
        if (ex >= 100u && ex <= 145u) hits++;
    }
    sd[t] = hits;
    __syncthreads();
    for (int s = 128; s > 0; s >>= 1) {
        if (t < s) sd[t] += sd[t + s];
        __syncthreads();
    }
    if (t == 0) *flag = (sd[0] > 3000) ? 1 : 0;
}

// ---------------------------------------------------------------------------
// Convert all 16 weight tensors to fp32 AND fp16 in ws (branch on flag).
// ---------------------------------------------------------------------------
struct WPtrs {
    const void* p[NW];
    int sz[NW];
    int off[NW];
};

__global__ void convert_k(WPtrs ptrs, float* __restrict__ outf, __half* __restrict__ outh,
                          const int* __restrict__ flag) {
    int which = blockIdx.y;
    int n = ptrs.sz[which];
    int i = blockIdx.x * 256 + threadIdx.x;
    if (i >= n) return;
    float v;
    if (*flag) v = __bfloat162float(((const __hip_bfloat16*)ptrs.p[which])[i]);
    else       v = ((const float*)ptrs.p[which])[i];
    outf[ptrs.off[which] + i] = v;
    outh[ptrs.off[which] + i] = __float2half(v);
}

// ---------------------------------------------------------------------------
// CSR build, R9 binning pipeline (R4-proven).
// ---------------------------------------------------------------------------
__global__ __launch_bounds__(512) void bhist_k(const int* __restrict__ srcI,
                                               int* __restrict__ bucketCnt,
                                               int Ee, int nbuck)
{
    __shared__ int bc[MAXB];
    int t = threadIdx.x;
    bc[t] = 0;
    __syncthreads();
    int base = blockIdx.x * TILE1;
    #pragma unroll
    for (int q = 0; q < 8; ++q) {
        int i = base + q * 512 + t;
        if (i < Ee) atomicAdd(&bc[srcI[i] >> 8], 1);
    }
    __syncthreads();
    if (t < nbuck && bc[t] > 0) atomicAdd(&bucketCnt[t], bc[t]);
}

__global__ __launch_bounds__(512) void bscan_k(
    const int* __restrict__ bucketCnt, int* __restrict__ bucketCur,
    int* __restrict__ bucketStart, int* __restrict__ rowStart,
    int nbuck, int Nn, int Ee)
{
    __shared__ int sd[MAXB];
    int t = threadIdx.x;
    int v = (t < nbuck) ? bucketCnt[t] : 0;
    sd[t] = v;
    __syncthreads();
    for (int off = 1; off < MAXB; off <<= 1) {
        int add = (t >= off) ? sd[t - off] : 0;
        __syncthreads();
        sd[t] += add;
        __syncthreads();
    }
    if (t < nbuck) {
        int excl = sd[t] - v;
        bucketCur[t] = excl;
        bucketStart[t] = excl;
    }
    if (t == 0) { bucketStart[nbuck] = Ee; rowStart[Nn] = Ee; }
}

__global__ __launch_bounds__(512) void pass1_k(
    const int* __restrict__ srcI, const int* __restrict__ dstI,
    int* __restrict__ bucketCur, uint32_t* __restrict__ pairs,
    int Ee, int nbuck)
{
    __shared__ int cntL[MAXB], scanL[MAXB], exclL[MAXB], curL[MAXB], gbaseL[MAXB];
    __shared__ uint32_t sortedV[TILE1];
    __shared__ uint16_t sortedB[TILE1];
    const int t = threadIdx.x;
    const int base = blockIdx.x * TILE1;
    cntL[t] = 0;
    __syncthreads();
    uint32_t vq[8]; int bq[8];
    #pragma unroll
    for (int q = 0; q < 8; ++q) {
        int i = base + q * 512 + t;
        if (i < Ee) {
            int s = srcI[i], d = dstI[i];
            bq[q] = s >> 8;
            vq[q] = ((uint32_t)d << 8) | (uint32_t)(s & 255);
            atomicAdd(&cntL[bq[q]], 1);
        } else bq[q] = -1;
    }
    __syncthreads();
    scanL[t] = cntL[t];
    __syncthreads();
    for (int off = 1; off < MAXB; off <<= 1) {
        int add = (t >= off) ? scanL[t - off] : 0;
        __syncthreads();
        scanL[t] += add;
        __syncthreads();
    }
    int excl = scanL[t] - cntL[t];
    exclL[t] = excl;
    curL[t] = excl;
    if (t < nbuck && cntL[t] > 0)
        gbaseL[t] = atomicAdd(&bucketCur[t], cntL[t]);
    __syncthreads();
    #pragma unroll
    for (int q = 0; q < 8; ++q) {
        if (bq[q] >= 0) {
            int pos = atomicAdd(&curL[bq[q]], 1);
            sortedV[pos] = vq[q];
            sortedB[pos] = (uint16_t)bq[q];
        }
    }
    __syncthreads();
    int tcount = min(TILE1, Ee - base);
    for (int j = t; j < tcount; j += 512) {
        int b = sortedB[j];
        pairs[gbaseL[b] + (j - exclL[b])] = sortedV[j];
    }
}

__global__ __launch_bounds__(256) void pass2_k(
    const uint32_t* __restrict__ pairs, const int* __restrict__ bucketStart,
    int* __restrict__ rowStart, int* __restrict__ colI, int Nn)
{
    __shared__ int ncnt[256], sd[256], lcur[256];
    int b = blockIdx.x, t = threadIdx.x;
    int n0 = b << 8;
    int s = bucketStart[b], e = bucketStart[b + 1];
    ncnt[t] = 0;
    __syncthreads();
    for (int p = s + t; p < e; p += 256)
        atomicAdd(&ncnt[pairs[p] & 255], 1);
    __syncthreads();
    int v = ncnt[t];
    sd[t] = v;
    __syncthreads();
    for (int off = 1; off < 256; off <<= 1) {
        int add = (t >= off) ? sd[t - off] : 0;
        __syncthreads();
        sd[t] += add;
        __syncthreads();
    }
    int start = s + sd[t] - v;
    lcur[t] = start;
    if (n0 + t < Nn) rowStart[n0 + t] = start;
    __syncthreads();
    for (int p = s + t; p < e; p += 256) {
        uint32_t pv = pairs[p];
        int q = atomicAdd(&lcur[pv & 255], 1);
        colI[q] = (int)(pv >> 8);
    }
}

// ---------------------------------------------------------------------------
// f16 MFMA GEMM, R16: SLICE-MAJOR h layout hS[8][M][32] (slice = 32 cols =
// 64B). BK=32 = exactly one slice -> the A-tile per K-step is ONE CONTIGUOUS
// 8KB slab (gload_lds from slab + row*64 + lane*16; LDS layout identical to
// before: [row][64B]). C-store (OMODE=1) re-addressed: thread's 16B goes to
// slice (col0>>5)+(cc>>2) at [gr][ (cc&3)*16 ]. AMODE=0 (row-major x input)
// staging unchanged. K-loop sync = R9 (fenced counted-vmcnt, proven).
// OMODE=1 score epilogue = R15 (acc-register based, proven).
// ---------------------------------------------------------------------------
template <int AMODE, int OMODE>
__global__ __launch_bounds__(256) void gemm_k(
    const void* __restrict__ Ap, const __half* __restrict__ B,
    const float* __restrict__ bias, void* __restrict__ Cp, int M,
    const int* __restrict__ flagp,
    const float* __restrict__ a1w, const float* __restrict__ a1b,
    const float* __restrict__ a2w, const float* __restrict__ a2b,
    float* __restrict__ a1v, __half* __restrict__ a2v)
{
    // 34.8 KB: staging dbuf uses [0,32K); epilogue Cs[128][136] reuses all.
    __shared__ __align__(16) char smem[128 * 136 * 2];
    const int tid  = threadIdx.x;
    const int row0 = blockIdx.y * 128;
    const int col0 = blockIdx.x * 128;
    const int wave = tid >> 6, lane = tid & 63;
    const int m0w = (wave & 1) * 64;
    const int n0w = (wave >> 1) * 64;
    const int lm = lane & 15, lg = lane >> 4;
    const int isbf = (AMODE == 0) ? *flagp : 0;

    const char* A = (const char*)Ap;
    // B gload lane mapping: lane -> (row base + lane>>2, kc = lane&3); 16B.
    const int lrow = wave * 32 + (lane >> 2);
    const int kcL  = lane & 3;
    const size_t brow0 = (size_t)(col0 + lrow) * CDIM;
    const size_t brow1 = (size_t)(col0 + lrow + 16) * CDIM;
    // A slab staging (AMODE=1): per-wave byte window [w*2048, w*2048+2048)
    // of the 8KB contiguous tile at slab kt + row0*64. Clamped to slab end.
    const int aoff0 = row0 * 64 + wave * 2048 + lane * 16;
    const int amax  = M * 64 - 16;

    f32x4 acc[4][4] = {};

    auto stageAB = [&](int buf, int kt) {
        char* Ab = smem + buf * 16384;
        char* Bb = Ab + 8192;
        const int k0 = kt * 32;
        if constexpr (AMODE == 1) {
            const size_t slab = (size_t)kt * M * 64;   // bytes
            __builtin_amdgcn_global_load_lds(
                GLOBAL_AS(A + slab + min(aoff0, amax)),
                LDS_AS(Ab + wave * 2048), 16, 0, 0);
            __builtin_amdgcn_global_load_lds(
                GLOBAL_AS(A + slab + min(aoff0 + 1024, amax)),
                LDS_AS(Ab + wave * 2048 + 1024), 16, 0, 0);
        } else {
            #pragma unroll
            for (int l = 0; l < 2; ++l) {
                int c = tid + l * 256;
                int m = c >> 2, kc = c & 3;
                int gr = row0 + m;
                uint4 q = make_uint4(0u, 0u, 0u, 0u);
                if (gr < M) {
                    __half hv[8];
                    if (isbf) {
                        const uint4 qb = *(const uint4*)((const __hip_bfloat16*)Ap
                                           + (size_t)gr * CDIM + k0 + kc * 8);
                        const uint32_t* w = (const uint32_t*)&qb;
                        #pragma unroll
                        for (int p = 0; p < 4; ++p) {
                            hv[2*p]   = __float2half(__uint_as_float((w[p] & 0xffffu) << 16));
                            hv[2*p+1] = __float2half(__uint_as_float(w[p] & 0xffff0000u));
                        }
                    } else {
                        const float* Af = (const float*)Ap + (size_t)gr * CDIM + k0 + kc * 8;
                        const float4 f0 = *(const float4*)Af;
                        const float4 f1 = *(const float4*)(Af + 4);
                        hv[0]=__float2half(f0.x); hv[1]=__float2half(f0.y);
                        hv[2]=__float2half(f0.z); hv[3]=__float2half(f0.w);
                        hv[4]=__float2half(f1.x); hv[5]=__float2half(f1.y);
                        hv[6]=__float2half(f1.z); hv[7]=__float2half(f1.w);
                    }
                    q = *(uint4*)hv;
                }
                *(uint4*)(Ab + m * 64 + kc * 16) = q;
            }
        }
        __builtin_amdgcn_global_load_lds(GLOBAL_AS((const __half*)B + brow0 + k0 + kcL * 8),
            LDS_AS(Bb + wave * 2048), 16, 0, 0);
        __builtin_amdgcn_global_load_lds(GLOBAL_AS((const __half*)B + brow1 + k0 + kcL * 8),
            LDS_AS(Bb + wave * 2048 + 1024), 16, 0, 0);
    };

    stageAB(0, 0);
    if constexpr (AMODE == 0) __syncthreads();
    int cur = 0;
    for (int kt = 0; kt < 8; ++kt) {
        if (kt < 7) stageAB(cur ^ 1, kt + 1);
        if constexpr (AMODE == 1) {
            // wait only for the PREVIOUS stage's 4 loads; new 4 stay in flight
            if (kt < 7) asm volatile("s_waitcnt vmcnt(4)" ::: "memory");
            else        asm volatile("s_waitcnt vmcnt(0)" ::: "memory");
            __builtin_amdgcn_s_barrier();
            asm volatile("" ::: "memory");      // fence: no mem op crosses up
            __builtin_amdgcn_sched_barrier(0);
        } else {
            __syncthreads();
        }
        const char* Ab = smem + cur * 16384;
        const char* Bb = Ab + 8192;
        f16x8 af[4], bfr[4];
        #pragma unroll
        for (int i = 0; i < 4; ++i)
            af[i] = *(const f16x8*)(Ab + (m0w + i * 16 + lm) * 64 + lg * 16);
        #pragma unroll
        for (int j = 0; j < 4; ++j)
            bfr[j] = *(const f16x8*)(Bb + (n0w + j * 16 + lm) * 64 + lg * 16);
        #pragma unroll
        for (int i = 0; i < 4; ++i)
            #pragma unroll
            for (int j = 0; j < 4; ++j)
                acc[i][j] = __builtin_amdgcn_mfma_f32_16x16x32_f16(
                    af[i], bfr[j], acc[i][j], 0, 0, 0);
        if constexpr (AMODE == 1) {
            __builtin_amdgcn_sched_barrier(0);
            asm volatile("" ::: "memory");      // fence: reads done before bar
            __builtin_amdgcn_s_barrier();
            asm volatile("" ::: "memory");      // fence: next stage stays below
        } else {
            __syncthreads();
        }
        cur ^= 1;
    }

    if constexpr (OMODE == 1) {
        // fp16 tile -> LDS; slice-major coalesced stores (64B per 4 threads)
        __half (*Cs)[136] = (__half(*)[136])smem;
        #pragma unroll
        for (int i = 0; i < 4; ++i)
            #pragma unroll
            for (int r = 0; r < 4; ++r) {
                int lr = m0w + i * 16 + lg * 4 + r;
                #pragma unroll
                for (int j = 0; j < 4; ++j)
                    Cs[lr][n0w + j * 16 + lm] = __float2half(acc[i][j][r]);
            }
        __syncthreads();
        char* C = (char*)Cp;
        #pragma unroll
        for (int l = 0; l < 8; ++l) {
            int c = tid + l * 256;
            int rr = c >> 4, cc = c & 15;
            int gr = row0 + rr;
            if (gr < M) {
                int q = (col0 >> 5) + (cc >> 2);        // slice index
                *(uint4*)(C + (size_t)q * M * 64 + (size_t)gr * 64 + (cc & 3) * 16)
                    = *(uint4*)(&Cs[rr][cc * 8]);
            }
        }
        // R15: fused scores from fp32 acc registers (no LDS reads, 8 w-loads)
        {
            const int hsel = wave >> 1;          // this wave's 64 cols = 1 head
            const int ghead = (col0 >> 6) + hsel;
            float wv1[4], wv2[4];
            #pragma unroll
            for (int j = 0; j < 4; ++j) {
                wv1[j] = a1w[ghead * 64 + j * 16 + lm];
                wv2[j] = a2w[ghead * 64 + j * 16 + lm];
            }
            const float b1s = a1b[ghead], b2s = a2b[ghead];
            #pragma unroll
            for (int i = 0; i < 4; ++i)
                #pragma unroll
                for (int r = 0; r < 4; ++r) {
                    float p1 = 0.f, p2 = 0.f;
                    #pragma unroll
                    for (int j = 0; j < 4; ++j) {
                        float v = acc[i][j][r];
                        p1 = fmaf(v, wv1[j], p1);
                        p2 = fmaf(v, wv2[j], p2);
                    }
                    #pragma unroll
                    for (int m = 1; m < 16; m <<= 1) {
                        p1 += __shfl_xor(p1, m);
                        p2 += __shfl_xor(p2, m);
                    }
                    int gr = row0 + m0w + i * 16 + lg * 4 + r;
                    if (lm == 0 && gr < M) {
                        a1v[(size_t)gr * H + ghead] = p1 + b1s;
                        a2v[(size_t)gr * H + ghead] = __float2half(p2 + b2s);
                    }
                }
        }
    } else {
        // collator + fused classifier partials (R8). feat stays in registers.
        const float* Wc4 = a1w;     // Wcls [OUTC][CDIM] fp32
        float* pcls = a1v;          // [M][4][OUTC] partials
        const int slot = blockIdx.x * 2 + (wave >> 1);
        float wv[OUTC][4];
        #pragma unroll
        for (int o = 0; o < OUTC; ++o)
            #pragma unroll
            for (int j = 0; j < 4; ++j)
                wv[o][j] = Wc4[o * CDIM + col0 + n0w + j * 16 + lm];
        #pragma unroll
        for (int i = 0; i < 4; ++i)
            #pragma unroll
            for (int r = 0; r < 4; ++r) {
                int grow = row0 + m0w + i * 16 + lg * 4 + r;
                if (grow < M) {
                    float po[OUTC] = {0.f, 0.f, 0.f, 0.f};
                    #pragma unroll
                    for (int j = 0; j < 4; ++j) {
                        int gcol = col0 + n0w + j * 16 + lm;
                        float t = fmaxf(acc[i][j][r] + bias[gcol], 0.f);
                        #pragma unroll
                        for (int o = 0; o < OUTC; ++o)
                            po[o] = fmaf(t, wv[o][j], po[o]);
                    }
                    #pragma unroll
                    for (int m = 1; m < 16; m <<= 1)
                        #pragma unroll
                        for (int o = 0; o < OUTC; ++o)
                            po[o] += __shfl_xor(po[o], m);
                    if (lm < OUTC) {
                        float v = (lm == 0) ? po[0] : (lm == 1) ? po[1]
                                : (lm == 2) ? po[2] : po[3];
                        pcls[((size_t)grow * 4 + slot) * OUTC + lm] = v;
                    }
                }
            }
        (void)Cp;
    }
}

// ---------------------------------------------------------------------------
// Edge aggregation, R16: XCD-SLICED over slice-major hS[8][Nn][32].
// slice = blockIdx & 7 -> the %8 XCD round-robin pins each 6.4MB slice to
// one XCD's 4MB L2 (was: every XCD gathering over the full 51.2MB, ~8%
// useful residency; L3->L2 service at 3.8 TB/s was the measured binder).
// One wave = one (node, slice); lane (e=lane>>2, c=lane&3) = edge e,
// 16B chunk c -> ALL 16 edges gathered per wave-instruction. Per-edge
// score computed inline (head = slice>>1, wave-uniform). Edge-reduce via
// shfl_xor 4/8/16/32; lanes e==0 write the 64B output chunk (hS layout).
// No barriers, no LDS. Tail masked by sv=0 + clamped slot (R11-proven).
// ---------------------------------------------------------------------------
__global__ __launch_bounds__(256) void agg_k(
    const __half* __restrict__ hS,
    const float* __restrict__ a1v, const __half* __restrict__ a2v,
    const int* __restrict__ rowStart, const int* __restrict__ colI,
    const float* __restrict__ bias, __half* __restrict__ outS, int relu, int Nn)
{
    const int tid = threadIdx.x;
    const int wave = tid >> 6, lane = tid & 63;
    const int s = blockIdx.x & 7;                 // slice (XCD-affine)
    const int n = (blockIdx.x >> 3) * 4 + wave;
    if (n >= Nn) return;
    const int head = s >> 1;
    const int e = lane >> 2, c = lane & 3;
    const size_t slab = (size_t)s * Nn * 32;      // halfs
    const __half* hsl = hS + slab;
    const float a1n = a1v[(size_t)n * H + head];
    const int p0 = rowStart[n], pe = rowStart[n + 1];

    float f0=0.f,f1=0.f,f2=0.f,f3=0.f,f4=0.f,f5=0.f,f6=0.f,f7=0.f,den=0.f;
    for (int base = p0; base < pe; base += 16) {
        const int cnt = pe - base;
        const int slot = base + ((e < cnt) ? e : 0);   // always < pe
        const int d = colI[slot];
        const uint4 u = *(const uint4*)(hsl + (size_t)d * 32 + c * 8);
        const float a2q = __half2float(a2v[(size_t)d * H + head]);
        float z = a1n + a2q;
        z = (z > 0.f) ? z : ALPHA * z;
        const float sv = (e < cnt) ? __expf(z) : 0.f;
        den += sv;
        f0 = fmaf(sv, __half2float(__ushort_as_half((ushort)(u.x & 0xffffu))), f0);
        f1 = fmaf(sv, __half2float(__ushort_as_half((ushort)(u.x >> 16))),    f1);
        f2 = fmaf(sv, __half2float(__ushort_as_half((ushort)(u.y & 0xffffu))), f2);
        f3 = fmaf(sv, __half2float(__ushort_as_half((ushort)(u.y >> 16))),    f3);
        f4 = fmaf(sv, __half2float(__ushort_as_half((ushort)(u.z & 0xffffu))), f4);
        f5 = fmaf(sv, __half2float(__ushort_as_half((ushort)(u.z >> 16))),    f5);
        f6 = fmaf(sv, __half2float(__ushort_as_half((ushort)(u.w & 0xffffu))), f6);
        f7 = fmaf(sv, __half2float(__ushort_as_half((ushort)(u.w >> 16))),    f7);
    }
    // reduce over the 16 e-lanes sharing chunk c (each e counted once)
    #pragma unroll
    for (int m = 4; m <= 32; m <<= 1) {
        den += __shfl_xor(den, m);
        f0 += __shfl_xor(f0, m); f1 += __shfl_xor(f1, m);
        f2 += __shfl_xor(f2, m); f3 += __shfl_xor(f3, m);
        f4 += __shfl_xor(f4, m); f5 += __shfl_xor(f5, m);
        f6 += __shfl_xor(f6, m); f7 += __shfl_xor(f7, m);
    }
    if (e == 0) {                                  // lanes 0..3
        den = (den > 0.f) ? den : 1.f;
        const float* bp = bias + s * 32 + c * 8;
        const float4 b0 = *(const float4*)bp;
        const float4 b1 = *(const float4*)(bp + 4);
        float r0 = f0 / den + b0.x, r1 = f1 / den + b0.y;
        float r2 = f2 / den + b0.z, r3 = f3 / den + b0.w;
        float r4 = f4 / den + b1.x, r5 = f5 / den + b1.y;
        float r6 = f6 / den + b1.z, r7 = f7 / den + b1.w;
        if (relu) {
            r0 = fmaxf(r0, 0.f); r1 = fmaxf(r1, 0.f);
            r2 = fmaxf(r2, 0.f); r3 = fmaxf(r3, 0.f);
            r4 = fmaxf(r4, 0.f); r5 = fmaxf(r5, 0.f);
            r6 = fmaxf(r6, 0.f); r7 = fmaxf(r7, 0.f);
        }
        ushort o[8];
        o[0] = __half_as_ushort(__float2half(r0));
        o[1] = __half_as_ushort(__float2half(r1));
        o[2] = __half_as_ushort(__float2half(r2));
        o[3] = __half_as_ushort(__float2half(r3));
        o[4] = __half_as_ushort(__float2half(r4));
        o[5] = __half_as_ushort(__float2half(r5));
        o[6] = __half_as_ushort(__float2half(r6));
        o[7] = __half_as_ushort(__float2half(r7));
        *(uint4*)(outS + slab + (size_t)n * 32 + c * 8) = *(uint4*)o;
    }
}

// ---------------------------------------------------------------------------
// Classifier finalize (R8): sum the 4 per-wave partials + bias; dtype per flag.
// ---------------------------------------------------------------------------
__global__ void cls2_k(const float* __restrict__ pcls, const float* __restrict__ bcls,
                       void* __restrict__ out, int Nn, const int* __restrict__ flagp)
{
    int n = blockIdx.x * 256 + threadIdx.x;
    if (n >= Nn) return;
    const float4 p0 = *(const float4*)(pcls + (size_t)n * 16);
    const float4 p1 = *(const float4*)(pcls + (size_t)n * 16 + 4);
    const float4 p2 = *(const float4*)(pcls + (size_t)n * 16 + 8);
    const float4 p3 = *(const float4*)(pcls + (size_t)n * 16 + 12);
    float r0 = p0.x + p1.x + p2.x + p3.x + bcls[0];
    float r1 = p0.y + p1.y + p2.y + p3.y + bcls[1];
    float r2 = p0.z + p1.z + p2.z + p3.z + bcls[2];
    float r3 = p0.w + p1.w + p2.w + p3.w + bcls[3];
    if (*flagp) {
        __hip_bfloat16* o = (__hip_bfloat16*)out + (size_t)n * OUTC;
        o[0] = __float2bfloat16(r0); o[1] = __float2bfloat16(r1);
        o[2] = __float2bfloat16(r2); o[3] = __float2bfloat16(r3);
    } else {
        float* o = (float*)out + (size_t)n * OUTC;
        o[0] = r0; o[1] = r1; o[2] = r2; o[3] = r3;
    }
}

// ---------------------------------------------------------------------------
extern "C" void kernel_launch(void* const* d_in, const int* in_sizes, int n_in,
                              void* d_out, int out_size, void* d_ws, size_t ws_size,
                              hipStream_t stream)
{
    const void* x  = d_in[0];
    const int*  ei = (const int*)d_in[1];

    const int Nn = in_sizes[0] / CDIM;   // 100000
    const int Ee = in_sizes[1] / 2;      // 1600000
    const int* srcI = ei;
    const int* dstI = ei + Ee;

    char* wsp = (char*)d_ws;
    size_t off = 0;
    auto alloc = [&](size_t bytes) -> void* {
        void* p = wsp + off;
        off += (bytes + 255) & ~(size_t)255;
        return p;
    };
    __half* hA   = (__half*)alloc((size_t)Nn * CDIM * 2);  // 51.2 MB (slice-major)
    __half* hB   = (__half*)alloc((size_t)Nn * CDIM * 2);  // 51.2 MB (slice-major)
    float*  a1v       = (float*)alloc((size_t)Nn * H * 4);
    __half* a2h       = (__half*)alloc((size_t)Nn * H * 2); // 0.8 MB fp16
    float*  pcls      = (float*)alloc((size_t)Nn * 4 * OUTC * 4); // 6.4 MB
    int*    rowStart  = (int*)alloc((size_t)(Nn + 1) * 4);
    int*    colI      = (int*)alloc((size_t)Ee * 4);       // 6.4 MB
    uint32_t* pairs   = (uint32_t*)alloc((size_t)Ee * 4);  // 6.4 MB packed
    int*    bucketCnt   = (int*)alloc(MAXB * 4);
    int*    bucketCur   = (int*)alloc(MAXB * 4);
    int*    bucketStart = (int*)alloc((MAXB + 1) * 4);
    int*    flag      = (int*)alloc(256);
    float*  wconv     = (float*)alloc((size_t)200000 * 4);
    __half* wh        = (__half*)alloc((size_t)200000 * 2);
    (void)ws_size; (void)n_in; (void)out_size;

    // dtype detect + weight conversion (proven machinery)
    detect_k<<<1, 256, 0, stream>>>((const uint32_t*)x, flag);
    WPtrs wp;
    int woff = 0;
    for (int i = 0; i < NW; ++i) {
        wp.p[i] = d_in[2 + i];
        wp.sz[i] = in_sizes[2 + i];
        wp.off[i] = woff;
        woff += in_sizes[2 + i];
    }
    {
        dim3 cgrid(256, NW);
        convert_k<<<cgrid, 256, 0, stream>>>(wp, wconv, wh, flag);
    }
    const float*  a11wf = wconv + wp.off[1];
    const float*  a11bf = wconv + wp.off[2];
    const float*  a12wf = wconv + wp.off[3];
    const float*  a12bf = wconv + wp.off[4];
    const float*  b1f   = wconv + wp.off[5];
    const float*  a21wf = wconv + wp.off[7];
    const float*  a21bf = wconv + wp.off[8];
    const float*  a22wf = wconv + wp.off[9];
    const float*  a22bf = wconv + wp.off[10];
    const float*  b2f   = wconv + wp.off[11];
    const float*  bcf   = wconv + wp.off[13];
    const float*  Wclsf = wconv + wp.off[14];
    const float*  bclsf = wconv + wp.off[15];
    const __half* W1h   = wh + wp.off[0];
    const __half* W2h   = wh + wp.off[6];
    const __half* Wch   = wh + wp.off[12];

    const int NB = (Nn + 255) / 256;          // node blocks (391)
    const int NBUCK = (Nn + 255) >> 8;        // buckets (391, <= MAXB)
    const int TB = (Ee + TILE1 - 1) / TILE1;  // edge tiles (391)

    // CSR build (R9 binning pipeline)
    hipMemsetAsync(bucketCnt, 0, MAXB * 4, stream);
    bhist_k<<<TB, 512, 0, stream>>>(srcI, bucketCnt, Ee, NBUCK);
    bscan_k<<<1, 512, 0, stream>>>(bucketCnt, bucketCur, bucketStart, rowStart,
                                   NBUCK, Nn, Ee);
    pass1_k<<<TB, 512, 0, stream>>>(srcI, dstI, bucketCur, pairs, Ee, NBUCK);
    pass2_k<<<NBUCK, 256, 0, stream>>>(pairs, bucketStart, rowStart, colI, Nn);

    dim3 ggrid(CDIM / 128, (Nn + 127) / 128);   // (2, 782)
    const int AB2 = ((Nn + 3) / 4) * 8;         // (node-group, slice) blocks

    // Layer 1: gemm(raw x) -> hA (+ fused scores); agg (sliced) -> hB
    gemm_k<0, 1><<<ggrid, 256, 0, stream>>>(x, W1h, nullptr, hA, Nn, flag,
                                            a11wf, a11bf, a12wf, a12bf, a1v, a2h);
    agg_k<<<AB2, 256, 0, stream>>>(hA, a1v, a2h, rowStart, colI, b1f, hB, 1, Nn);

    // Layer 2: gemm(hB) -> hA (+ fused scores); agg (sliced) -> hB
    gemm_k<1, 1><<<ggrid, 256, 0, stream>>>(hB, W2h, nullptr, hA, Nn, flag,
                                            a21wf, a21bf, a22wf, a22bf, a1v, a2h);
    agg_k<<<AB2, 256, 0, stream>>>(hA, a1v, a2h, rowStart, colI, b2f, hB, 0, Nn);

    // Collator + fused classifier partials; then finalize
    gemm_k<1, 0><<<ggrid, 256, 0, stream>>>(hB, Wch, bcf, nullptr, Nn, flag,
                                            Wclsf, nullptr, nullptr, nullptr,
                                            pcls, nullptr);
    cls2_k<<<NB, 256, 0, stream>>>(pcls, bclsf, d_out, Nn, flag);
}

// Round 12
// 616.135 us; speedup vs baseline: 1.6585x; 1.6585x over previous
//
#include <hip/hip_runtime.h>
#include <hip/hip_bf16.h>
#include <hip/hip_fp16.h>
#include <stdint.h>

#define H 4
#define HID 64
#define CDIM 256   /* = H*HID = IN = FC */
#define OUTC 4
#define ALPHA 0.2f
#define NW 16      /* number of float weight inputs (d_in[2..17]) */
#define MAXB 512   /* max buckets; NBUCK = ceil(Nn/256) <= 512 for Nn <= 131072 */
#define TILE1 4096 /* edges per pass1 tile (8 per thread x 512 threads) */

typedef __attribute__((ext_vector_type(8))) _Float16 f16x8;
typedef __attribute__((ext_vector_type(4))) float f32x4;

#define GLOBAL_AS(p) ((const __attribute__((address_space(1))) void*)(p))
#define LDS_AS(p)    ((__attribute__((address_space(3))) void*)(p))

// ---------------------------------------------------------------------------
// dtype detection (R2/R4/R5-proven; real answer on this harness: fp32, flag=0)
// ---------------------------------------------------------------------------
__global__ void detect_k(const uint32_t* __restrict__ xw, int* __restrict__ flag) {
    __shared__ int sd[256];
    int t = threadIdx.x;
    int hits = 0;
    for (int i = 0; i < 16; ++i) {
        uint32_t w = xw[t * 16 + i];
        uint32_t ex = (w >> 7) & 0xffu;
        if (ex >= 100u && ex <= 145u) hits++;
    }
    sd[t] = hits;
    __syncthreads();
    for (int s = 128; s > 0; s >>= 1) {
        if (t < s) sd[t] += sd[t + s];
        __syncthreads();
    }
    if (t == 0) *flag = (sd[0] > 3000) ? 1 : 0;
}

// ---------------------------------------------------------------------------
// Convert all 16 weight tensors to fp32 AND fp16 in ws (branch on flag).
// ---------------------------------------------------------------------------
struct WPtrs {
    const void* p[NW];
    int sz[NW];
    int off[NW];
};

__global__ void convert_k(WPtrs ptrs, float* __restrict__ outf, __half* __restrict__ outh,
                          const int* __restrict__ flag) {
    int which = blockIdx.y;
    int n = ptrs.sz[which];
    int i = blockIdx.x * 256 + threadIdx.x;
    if (i >= n) return;
    float v;
    if (*flag) v = __bfloat162float(((const __hip_bfloat16*)ptrs.p[which])[i]);
    else       v = ((const float*)ptrs.p[which])[i];
    outf[ptrs.off[which] + i] = v;
    outh[ptrs.off[which] + i] = __float2half(v);
}

// ---------------------------------------------------------------------------
// CSR build, R9 binning pipeline (R4-proven).
// ---------------------------------------------------------------------------
__global__ __launch_bounds__(512) void bhist_k(const int* __restrict__ srcI,
                                               int* __restrict__ bucketCnt,
                                               int Ee, int nbuck)
{
    __shared__ int bc[MAXB];
    int t = threadIdx.x;
    bc[t] = 0;
    __syncthreads();
    int base = blockIdx.x * TILE1;
    #pragma unroll
    for (int q = 0; q < 8; ++q) {
        int i = base + q * 512 + t;
        if (i < Ee) atomicAdd(&bc[srcI[i] >> 8], 1);
    }
    __syncthreads();
    if (t < nbuck && bc[t] > 0) atomicAdd(&bucketCnt[t], bc[t]);
}

__global__ __launch_bounds__(512) void bscan_k(
    const int* __restrict__ bucketCnt, int* __restrict__ bucketCur,
    int* __restrict__ bucketStart, int* __restrict__ rowStart,
    int nbuck, int Nn, int Ee)
{
    __shared__ int sd[MAXB];
    int t = threadIdx.x;
    int v = (t < nbuck) ? bucketCnt[t] : 0;
    sd[t] = v;
    __syncthreads();
    for (int off = 1; off < MAXB; off <<= 1) {
        int add = (t >= off) ? sd[t - off] : 0;
        __syncthreads();
        sd[t] += add;
        __syncthreads();
    }
    if (t < nbuck) {
        int excl = sd[t] - v;
        bucketCur[t] = excl;
        bucketStart[t] = excl;
    }
    if (t == 0) { bucketStart[nbuck] = Ee; rowStart[Nn] = Ee; }
}

__global__ __launch_bounds__(512) void pass1_k(
    const int* __restrict__ srcI, const int* __restrict__ dstI,
    int* __restrict__ bucketCur, uint32_t* __restrict__ pairs,
    int Ee, int nbuck)
{
    __shared__ int cntL[MAXB], scanL[MAXB], exclL[MAXB], curL[MAXB], gbaseL[MAXB];
    __shared__ uint32_t sortedV[TILE1];
    __shared__ uint16_t sortedB[TILE1];
    const int t = threadIdx.x;
    const int base = blockIdx.x * TILE1;
    cntL[t] = 0;
    __syncthreads();
    uint32_t vq[8]; int bq[8];
    #pragma unroll
    for (int q = 0; q < 8; ++q) {
        int i = base + q * 512 + t;
        if (i < Ee) {
            int s = srcI[i], d = dstI[i];
            bq[q] = s >> 8;
            vq[q] = ((uint32_t)d << 8) | (uint32_t)(s & 255);
            atomicAdd(&cntL[bq[q]], 1);
        } else bq[q] = -1;
    }
    __syncthreads();
    scanL[t] = cntL[t];
    __syncthreads();
    for (int off = 1; off < MAXB; off <<= 1) {
        int add = (t >= off) ? scanL[t - off] : 0;
        __syncthreads();
        scanL[t] += add;
        __syncthreads();
    }
    int excl = scanL[t] - cntL[t];
    exclL[t] = excl;
    curL[t] = excl;
    if (t < nbuck && cntL[t] > 0)
        gbaseL[t] = atomicAdd(&bucketCur[t], cntL[t]);
    __syncthreads();
    #pragma unroll
    for (int q = 0; q < 8; ++q) {
        if (bq[q] >= 0) {
            int pos = atomicAdd(&curL[bq[q]], 1);
            sortedV[pos] = vq[q];
            sortedB[pos] = (uint16_t)bq[q];
        }
    }
    __syncthreads();
    int tcount = min(TILE1, Ee - base);
    for (int j = t; j < tcount; j += 512) {
        int b = sortedB[j];
        pairs[gbaseL[b] + (j - exclL[b])] = sortedV[j];
    }
}

__global__ __launch_bounds__(256) void pass2_k(
    const uint32_t* __restrict__ pairs, const int* __restrict__ bucketStart,
    int* __restrict__ rowStart, int* __restrict__ colI, int Nn)
{
    __shared__ int ncnt[256], sd[256], lcur[256];
    int b = blockIdx.x, t = threadIdx.x;
    int n0 = b << 8;
    int s = bucketStart[b], e = bucketStart[b + 1];
    ncnt[t] = 0;
    __syncthreads();
    for (int p = s + t; p < e; p += 256)
        atomicAdd(&ncnt[pairs[p] & 255], 1);
    __syncthreads();
    int v = ncnt[t];
    sd[t] = v;
    __syncthreads();
    for (int off = 1; off < 256; off <<= 1) {
        int add = (t >= off) ? sd[t - off] : 0;
        __syncthreads();
        sd[t] += add;
        __syncthreads();
    }
    int start = s + sd[t] - v;
    lcur[t] = start;
    if (n0 + t < Nn) rowStart[n0 + t] = start;
    __syncthreads();
    for (int p = s + t; p < e; p += 256) {
        uint32_t pv = pairs[p];
        int q = atomicAdd(&lcur[pv & 255], 1);
        colI[q] = (int)(pv >> 8);
    }
}

// ---------------------------------------------------------------------------
// f16 MFMA GEMM, R17 = R15 (proven) + XCD-PAIR grid swizzle.
// Old grid (2,782): the two col-blocks of one A-row-tile got linear IDs
// 2y,2y+1 -> DIFFERENT XCDs under %8 round-robin -> each A-tile filled into
// two L2s (A fills ~102MB/gemm instead of 51). New 1-D grid maps blocks
// {k, k+8} (same id%8 -> same XCD) to the two col-blocks of one row-tile.
// K-loop sync = R9 fenced counted-vmcnt (proven). OMODE=1 score epilogue =
// R15 acc-register (proven). agg/h layout: row-major (R11 slice REVERTED).
// ---------------------------------------------------------------------------
template <int AMODE, int OMODE>
__global__ __launch_bounds__(256) void gemm_k(
    const void* __restrict__ Ap, const __half* __restrict__ B,
    const float* __restrict__ bias, void* __restrict__ Cp, int M,
    const int* __restrict__ flagp,
    const float* __restrict__ a1w, const float* __restrict__ a1b,
    const float* __restrict__ a2w, const float* __restrict__ a2b,
    float* __restrict__ a1v, __half* __restrict__ a2v)
{
    // 34.8 KB: staging dbuf uses [0,32K); epilogue Cs[128][136] reuses all.
    __shared__ __align__(16) char smem[128 * 136 * 2];
    const int tid  = threadIdx.x;
    // XCD-pair decode: blocks {k,k+8} share an XCD and a row-tile.
    int r, cblk;
    {
        const int bid = blockIdx.x;
        const int nrow = gridDim.x >> 1;          // grid = nrow*2 blocks
        const int nfull16 = (nrow >> 3) << 4;     // full 8-row groups * 16
        if (bid < nfull16) { r = (bid >> 4) * 8 + (bid & 7); cblk = (bid >> 3) & 1; }
        else { int t2 = bid - nfull16; r = (nfull16 >> 1) + (t2 >> 1); cblk = t2 & 1; }
    }
    const int row0 = r * 128;
    const int col0 = cblk * 128;
    const int wave = tid >> 6, lane = tid & 63;
    const int m0w = (wave & 1) * 64;
    const int n0w = (wave >> 1) * 64;
    const int lm = lane & 15, lg = lane >> 4;
    const int isbf = (AMODE == 0) ? *flagp : 0;

    const __half* A = (const __half*)Ap;
    // gload lane mapping: lane -> (row base + lane>>2, kc = lane&3); 16B each.
    const int lrow = wave * 32 + (lane >> 2);
    const int kcL  = lane & 3;
    // A source rows clamped (OOB rows discarded at epilogue)
    const size_t arow0 = (size_t)min(row0 + lrow,      M - 1) * CDIM;
    const size_t arow1 = (size_t)min(row0 + lrow + 16, M - 1) * CDIM;
    const size_t brow0 = (size_t)(col0 + lrow) * CDIM;
    const size_t brow1 = (size_t)(col0 + lrow + 16) * CDIM;

    f32x4 acc[4][4] = {};

    auto stageAB = [&](int buf, int k0) {
        char* Ab = smem + buf * 16384;
        char* Bb = Ab + 8192;
        if constexpr (AMODE == 1) {
            __builtin_amdgcn_global_load_lds(GLOBAL_AS(A + arow0 + k0 + kcL * 8),
                LDS_AS(Ab + wave * 2048), 16, 0, 0);
            __builtin_amdgcn_global_load_lds(GLOBAL_AS(A + arow1 + k0 + kcL * 8),
                LDS_AS(Ab + wave * 2048 + 1024), 16, 0, 0);
        } else {
            #pragma unroll
            for (int l = 0; l < 2; ++l) {
                int c = tid + l * 256;
                int m = c >> 2, kc = c & 3;
                int gr = row0 + m;
                uint4 q = make_uint4(0u, 0u, 0u, 0u);
                if (gr < M) {
                    __half hv[8];
                    if (isbf) {
                        const uint4 qb = *(const uint4*)((const __hip_bfloat16*)Ap
                                           + (size_t)gr * CDIM + k0 + kc * 8);
                        const uint32_t* w = (const uint32_t*)&qb;
                        #pragma unroll
                        for (int p = 0; p < 4; ++p) {
                            hv[2*p]   = __float2half(__uint_as_float((w[p] & 0xffffu) << 16));
                            hv[2*p+1] = __float2half(__uint_as_float(w[p] & 0xffff0000u));
                        }
                    } else {
                        const float* Af = (const float*)Ap + (size_t)gr * CDIM + k0 + kc * 8;
                        const float4 f0 = *(const float4*)Af;
                        const float4 f1 = *(const float4*)(Af + 4);
                        hv[0]=__float2half(f0.x); hv[1]=__float2half(f0.y);
                        hv[2]=__float2half(f0.z); hv[3]=__float2half(f0.w);
                        hv[4]=__float2half(f1.x); hv[5]=__float2half(f1.y);
                        hv[6]=__float2half(f1.z); hv[7]=__float2half(f1.w);
                    }
                    q = *(uint4*)hv;
                }
                *(uint4*)(Ab + m * 64 + kc * 16) = q;
            }
        }
        __builtin_amdgcn_global_load_lds(GLOBAL_AS(B + brow0 + k0 + kcL * 8),
            LDS_AS(Bb + wave * 2048), 16, 0, 0);
        __builtin_amdgcn_global_load_lds(GLOBAL_AS(B + brow1 + k0 + kcL * 8),
            LDS_AS(Bb + wave * 2048 + 1024), 16, 0, 0);
    };

    stageAB(0, 0);
    if constexpr (AMODE == 0) __syncthreads();
    int cur = 0;
    for (int kt = 0; kt < 8; ++kt) {
        if (kt < 7) stageAB(cur ^ 1, (kt + 1) * 32);
        if constexpr (AMODE == 1) {
            // wait only for the PREVIOUS stage's 4 loads; new 4 stay in flight
            if (kt < 7) asm volatile("s_waitcnt vmcnt(4)" ::: "memory");
            else        asm volatile("s_waitcnt vmcnt(0)" ::: "memory");
            __builtin_amdgcn_s_barrier();
            asm volatile("" ::: "memory");      // fence: no mem op crosses up
            __builtin_amdgcn_sched_barrier(0);
        } else {
            __syncthreads();
        }
        const char* Ab = smem + cur * 16384;
        const char* Bb = Ab + 8192;
        f16x8 af[4], bfr[4];
        #pragma unroll
        for (int i = 0; i < 4; ++i)
            af[i] = *(const f16x8*)(Ab + (m0w + i * 16 + lm) * 64 + lg * 16);
        #pragma unroll
        for (int j = 0; j < 4; ++j)
            bfr[j] = *(const f16x8*)(Bb + (n0w + j * 16 + lm) * 64 + lg * 16);
        #pragma unroll
        for (int i = 0; i < 4; ++i)
            #pragma unroll
            for (int j = 0; j < 4; ++j)
                acc[i][j] = __builtin_amdgcn_mfma_f32_16x16x32_f16(
                    af[i], bfr[j], acc[i][j], 0, 0, 0);
        if constexpr (AMODE == 1) {
            __builtin_amdgcn_sched_barrier(0);
            asm volatile("" ::: "memory");      // fence: reads done before bar
            __builtin_amdgcn_s_barrier();
            asm volatile("" ::: "memory");      // fence: next stage stays below
        } else {
            __syncthreads();
        }
        cur ^= 1;
    }

    if constexpr (OMODE == 1) {
        // fp16 tile -> LDS; n-major coalesced stores (unchanged, proven)
        __half (*Cs)[136] = (__half(*)[136])smem;
        #pragma unroll
        for (int i = 0; i < 4; ++i)
            #pragma unroll
            for (int r2 = 0; r2 < 4; ++r2) {
                int lr = m0w + i * 16 + lg * 4 + r2;
                #pragma unroll
                for (int j = 0; j < 4; ++j)
                    Cs[lr][n0w + j * 16 + lm] = __float2half(acc[i][j][r2]);
            }
        __syncthreads();
        __half* C = (__half*)Cp;
        #pragma unroll
        for (int l = 0; l < 8; ++l) {
            int c = tid + l * 256;
            int rr = c >> 4, cc = c & 15;
            int gr = row0 + rr;
            if (gr < M)
                *(uint4*)(C + (size_t)gr * CDIM + col0 + cc * 8) = *(uint4*)(&Cs[rr][cc * 8]);
        }
        // R15: fused scores from fp32 acc registers (no LDS reads, 8 w-loads)
        {
            const int hsel = wave >> 1;          // this wave's 64 cols = 1 head
            const int ghead = (col0 >> 6) + hsel;
            float wv1[4], wv2[4];
            #pragma unroll
            for (int j = 0; j < 4; ++j) {
                wv1[j] = a1w[ghead * 64 + j * 16 + lm];
                wv2[j] = a2w[ghead * 64 + j * 16 + lm];
            }
            const float b1s = a1b[ghead], b2s = a2b[ghead];
            #pragma unroll
            for (int i = 0; i < 4; ++i)
                #pragma unroll
                for (int r2 = 0; r2 < 4; ++r2) {
                    float p1 = 0.f, p2 = 0.f;
                    #pragma unroll
                    for (int j = 0; j < 4; ++j) {
                        float v = acc[i][j][r2];
                        p1 = fmaf(v, wv1[j], p1);
                        p2 = fmaf(v, wv2[j], p2);
                    }
                    #pragma unroll
                    for (int m = 1; m < 16; m <<= 1) {
                        p1 += __shfl_xor(p1, m);
                        p2 += __shfl_xor(p2, m);
                    }
                    int gr = row0 + m0w + i * 16 + lg * 4 + r2;
                    if (lm == 0 && gr < M) {
                        a1v[(size_t)gr * H + ghead] = p1 + b1s;
                        a2v[(size_t)gr * H + ghead] = __float2half(p2 + b2s);
                    }
                }
        }
    } else {
        // collator + fused classifier partials (R8). feat stays in registers.
        const float* Wc4 = a1w;     // Wcls [OUTC][CDIM] fp32
        float* pcls = a1v;          // [M][4][OUTC] partials
        const int slot = cblk * 2 + (wave >> 1);
        float wv[OUTC][4];
        #pragma unroll
        for (int o = 0; o < OUTC; ++o)
            #pragma unroll
            for (int j = 0; j < 4; ++j)
                wv[o][j] = Wc4[o * CDIM + col0 + n0w + j * 16 + lm];
        #pragma unroll
        for (int i = 0; i < 4; ++i)
            #pragma unroll
            for (int r2 = 0; r2 < 4; ++r2) {
                int grow = row0 + m0w + i * 16 + lg * 4 + r2;
                if (grow < M) {
                    float po[OUTC] = {0.f, 0.f, 0.f, 0.f};
                    #pragma unroll
                    for (int j = 0; j < 4; ++j) {
                        int gcol = col0 + n0w + j * 16 + lm;
                        float t = fmaxf(acc[i][j][r2] + bias[gcol], 0.f);
                        #pragma unroll
                        for (int o = 0; o < OUTC; ++o)
                            po[o] = fmaf(t, wv[o][j], po[o]);
                    }
                    #pragma unroll
                    for (int m = 1; m < 16; m <<= 1)
                        #pragma unroll
                        for (int o = 0; o < OUTC; ++o)
                            po[o] += __shfl_xor(po[o], m);
                    if (lm < OUTC) {
                        float v = (lm == 0) ? po[0] : (lm == 1) ? po[1]
                                : (lm == 2) ? po[2] : po[3];
                        pcls[((size_t)grow * 4 + slot) * OUTC + lm] = v;
                    }
                }
            }
        (void)Cp;
    }
}

// ---------------------------------------------------------------------------
// Edge aggregation (R11-slice REVERTED; back to R10 row-major, proven 5x at
// the ~3.8 TB/s random-line service ceiling: 417MB fills -> ~125us. FROZEN.)
// ---------------------------------------------------------------------------
__global__ __launch_bounds__(256) void agg_k(
    const __half* __restrict__ h,
    const float* __restrict__ a1v, const __half* __restrict__ a2v,
    const int* __restrict__ rowStart, const int* __restrict__ colI,
    const float* __restrict__ bias, __half* __restrict__ outp, int relu, int Nn)
{
    int tid = threadIdx.x;
    int wave = tid >> 6, lane = tid & 63;
    int n = blockIdx.x * 4 + wave;
    if (n >= Nn) return;
    int head = lane >> 4;
    int s = rowStart[n], e = rowStart[n + 1];
    float ac0 = 0.f, ac1 = 0.f, ac2 = 0.f, ac3 = 0.f, den = 0.f;
    const __half* hl = h + lane * 4;
    const float a1n = a1v[(size_t)n * H + head];

    for (int p0 = s; p0 < e; p0 += 8) {
        const int cnt = e - p0;            // wave-uniform; >= 1
        int d[8]; float a2q[8]; ushort4 u[8];
        #pragma unroll
        for (int q = 0; q < 8; ++q) {
            int p = p0 + ((q < cnt) ? q : 0);   // clamped: always < e
            d[q] = colI[p];
        }
        #pragma unroll
        for (int q = 0; q < 8; ++q) {
            u[q] = *(const ushort4*)(hl + (size_t)d[q] * CDIM);
            a2q[q] = __half2float(a2v[(size_t)d[q] * H + head]);
        }
        #pragma unroll
        for (int q = 0; q < 8; ++q) {
            float z = a1n + a2q[q];
            z = (z > 0.f) ? z : ALPHA * z;
            float svq = (q < cnt) ? __expf(z) : 0.f;
            den += svq;
            ac0 = fmaf(svq, __half2float(__ushort_as_half(u[q].x)), ac0);
            ac1 = fmaf(svq, __half2float(__ushort_as_half(u[q].y)), ac1);
            ac2 = fmaf(svq, __half2float(__ushort_as_half(u[q].z)), ac2);
            ac3 = fmaf(svq, __half2float(__ushort_as_half(u[q].w)), ac3);
        }
    }

    den = (den > 0.f) ? den : 1.f;
    const float4 b4 = *(const float4*)(bias + lane * 4);
    float r0 = ac0 / den + b4.x;
    float r1 = ac1 / den + b4.y;
    float r2 = ac2 / den + b4.z;
    float r3 = ac3 / den + b4.w;
    if (relu) {
        r0 = fmaxf(r0, 0.f); r1 = fmaxf(r1, 0.f);
        r2 = fmaxf(r2, 0.f); r3 = fmaxf(r3, 0.f);
    }
    ushort4 o;
    o.x = __half_as_ushort(__float2half(r0));
    o.y = __half_as_ushort(__float2half(r1));
    o.z = __half_as_ushort(__float2half(r2));
    o.w = __half_as_ushort(__float2half(r3));
    *(ushort4*)(outp + (size_t)n * CDIM + lane * 4) = o;
}

// ---------------------------------------------------------------------------
// Classifier finalize (R8): sum the 4 per-wave partials + bias; dtype per flag.
// ---------------------------------------------------------------------------
__global__ void cls2_k(const float* __restrict__ pcls, const float* __restrict__ bcls,
                       void* __restrict__ out, int Nn, const int* __restrict__ flagp)
{
    int n = blockIdx.x * 256 + threadIdx.x;
    if (n >= Nn) return;
    const float4 p0 = *(const float4*)(pcls + (size_t)n * 16);
    const float4 p1 = *(const float4*)(pcls + (size_t)n * 16 + 4);
    const float4 p2 = *(const float4*)(pcls + (size_t)n * 16 + 8);
    const float4 p3 = *(const float4*)(pcls + (size_t)n * 16 + 12);
    float r0 = p0.x + p1.x + p2.x + p3.x + bcls[0];
    float r1 = p0.y + p1.y + p2.y + p3.y + bcls[1];
    float r2 = p0.z + p1.z + p2.z + p3.z + bcls[2];
    float r3 = p0.w + p1.w + p2.w + p3.w + bcls[3];
    if (*flagp) {
        __hip_bfloat16* o = (__hip_bfloat16*)out + (size_t)n * OUTC;
        o[0] = __float2bfloat16(r0); o[1] = __float2bfloat16(r1);
        o[2] = __float2bfloat16(r2); o[3] = __float2bfloat16(r3);
    } else {
        float* o = (float*)out + (size_t)n * OUTC;
        o[0] = r0; o[1] = r1; o[2] = r2; o[3] = r3;
    }
}

// ---------------------------------------------------------------------------
extern "C" void kernel_launch(void* const* d_in, const int* in_sizes, int n_in,
                              void* d_out, int out_size, void* d_ws, size_t ws_size,
                              hipStream_t stream)
{
    const void* x  = d_in[0];
    const int*  ei = (const int*)d_in[1];

    const int Nn = in_sizes[0] / CDIM;   // 100000
    const int Ee = in_sizes[1] / 2;      // 1600000
    const int* srcI = ei;
    const int* dstI = ei + Ee;

    char* wsp = (char*)d_ws;
    size_t off = 0;
    auto alloc = [&](size_t bytes) -> void* {
        void* p = wsp + off;
        off += (bytes + 255) & ~(size_t)255;
        return p;
    };
    __half* hA   = (__half*)alloc((size_t)Nn * CDIM * 2);  // 51.2 MB
    __half* hB   = (__half*)alloc((size_t)Nn * CDIM * 2);  // 51.2 MB
    float*  a1v       = (float*)alloc((size_t)Nn * H * 4);
    __half* a2h       = (__half*)alloc((size_t)Nn * H * 2); // 0.8 MB fp16
    float*  pcls      = (float*)alloc((size_t)Nn * 4 * OUTC * 4); // 6.4 MB
    int*    rowStart  = (int*)alloc((size_t)(Nn + 1) * 4);
    int*    colI      = (int*)alloc((size_t)Ee * 4);       // 6.4 MB
    uint32_t* pairs   = (uint32_t*)alloc((size_t)Ee * 4);  // 6.4 MB packed
    int*    bucketCnt   = (int*)alloc(MAXB * 4);
    int*    bucketCur   = (int*)alloc(MAXB * 4);
    int*    bucketStart = (int*)alloc((MAXB + 1) * 4);
    int*    flag      = (int*)alloc(256);
    float*  wconv     = (float*)alloc((size_t)200000 * 4);
    __half* wh        = (__half*)alloc((size_t)200000 * 2);
    (void)ws_size; (void)n_in; (void)out_size;

    // dtype detect + weight conversion (proven machinery)
    detect_k<<<1, 256, 0, stream>>>((const uint32_t*)x, flag);
    WPtrs wp;
    int woff = 0;
    for (int i = 0; i < NW; ++i) {
        wp.p[i] = d_in[2 + i];
        wp.sz[i] = in_sizes[2 + i];
        wp.off[i] = woff;
        woff += in_sizes[2 + i];
    }
    {
        dim3 cgrid(256, NW);
        convert_k<<<cgrid, 256, 0, stream>>>(wp, wconv, wh, flag);
    }
    const float*  a11wf = wconv + wp.off[1];
    const float*  a11bf = wconv + wp.off[2];
    const float*  a12wf = wconv + wp.off[3];
    const float*  a12bf = wconv + wp.off[4];
    const float*  b1f   = wconv + wp.off[5];
    const float*  a21wf = wconv + wp.off[7];
    const float*  a21bf = wconv + wp.off[8];
    const float*  a22wf = wconv + wp.off[9];
    const float*  a22bf = wconv + wp.off[10];
    const float*  b2f   = wconv + wp.off[11];
    const float*  bcf   = wconv + wp.off[13];
    const float*  Wclsf = wconv + wp.off[14];
    const float*  bclsf = wconv + wp.off[15];
    const __half* W1h   = wh + wp.off[0];
    const __half* W2h   = wh + wp.off[6];
    const __half* Wch   = wh + wp.off[12];

    const int NB = (Nn + 255) / 256;          // node blocks (391)
    const int NBUCK = (Nn + 255) >> 8;        // buckets (391, <= MAXB)
    const int TB = (Ee + TILE1 - 1) / TILE1;  // edge tiles (391)

    // CSR build (R9 binning pipeline)
    hipMemsetAsync(bucketCnt, 0, MAXB * 4, stream);
    bhist_k<<<TB, 512, 0, stream>>>(srcI, bucketCnt, Ee, NBUCK);
    bscan_k<<<1, 512, 0, stream>>>(bucketCnt, bucketCur, bucketStart, rowStart,
                                   NBUCK, Nn, Ee);
    pass1_k<<<TB, 512, 0, stream>>>(srcI, dstI, bucketCur, pairs, Ee, NBUCK);
    pass2_k<<<NBUCK, 256, 0, stream>>>(pairs, bucketStart, rowStart, colI, Nn);

    const int NROW = (Nn + 127) / 128;          // 782
    dim3 ggrid(NROW * 2);                       // 1-D, XCD-pair swizzled
    const int AB = (Nn + 3) / 4;                // 4 nodes (waves) per block

    // Layer 1: gemm(raw x) -> hA (+ fused scores); agg (fused escore) -> hB
    gemm_k<0, 1><<<ggrid, 256, 0, stream>>>(x, W1h, nullptr, hA, Nn, flag,
                                            a11wf, a11bf, a12wf, a12bf, a1v, a2h);
    agg_k<<<AB, 256, 0, stream>>>(hA, a1v, a2h, rowStart, colI, b1f, hB, 1, Nn);

    // Layer 2: gemm(hB) -> hA (+ fused scores); agg (fused escore) -> hB
    gemm_k<1, 1><<<ggrid, 256, 0, stream>>>(hB, W2h, nullptr, hA, Nn, flag,
                                            a21wf, a21bf, a22wf, a22bf, a1v, a2h);
    agg_k<<<AB, 256, 0, stream>>>(hA, a1v, a2h, rowStart, colI, b2f, hB, 0, Nn);

    // Collator + fused classifier partials; then finalize
    gemm_k<1, 0><<<ggrid, 256, 0, stream>>>(hB, Wch, bcf, nullptr, Nn, flag,
                                            Wclsf, nullptr, nullptr, nullptr,
                                            pcls, nullptr);
    cls2_k<<<NB, 256, 0, stream>>>(pcls, bclsf, d_out, Nn, flag);
}